// Round 7
// baseline (358.536 us; speedup 1.0000x reference)
//
#include <hip/hip_runtime.h>
#include <hip/hip_bf16.h>

typedef unsigned short ushort_t;
typedef __attribute__((ext_vector_type(8))) short short8;
typedef __attribute__((ext_vector_type(4))) float float4v;

__device__ __forceinline__ float bfu_lo(unsigned u) {
    return __uint_as_float(u << 16);
}
__device__ __forceinline__ float bfu_hi(unsigned u) {
    return __uint_as_float(u & 0xffff0000u);
}
__device__ __forceinline__ ushort_t f2bf(float f) {
    __hip_bfloat16 h = __float2bfloat16(f);
    return *reinterpret_cast<ushort_t*>(&h);
}

// Wall layout per layer: 14 col-tiles (210 cols used), tile = 1024 ushorts:
//   idx = ct*1024 + kch*512 + lane*8 + j   (k = kch*32 + quad*8 + j, col = ct*16 + nn)
// cols: 0..127 qk2 (composed 0.125*Wq·Wk^T) | 128..191 skip | 192..209 qc (composed ea)
// Edge record (32 B, sector-aligned): +0 src byte-offset (int), +16 ea bf16x8.

// ---------------- fused setup ----------------

__global__ __launch_bounds__(256) void setup_kernel(
    const float* __restrict__ x, const float* __restrict__ node_W,
    const float* __restrict__ node_b,
    const float* __restrict__ edge_W, const float* __restrict__ edge_b,
    const float* __restrict__ We, const float* __restrict__ be,
    const float* __restrict__ Wq, const float* __restrict__ bq,
    const float* __restrict__ Wk, const float* __restrict__ bk,
    const float* __restrict__ Wv, const float* __restrict__ bv,
    const float* __restrict__ Wskip, const float* __restrict__ bskip,
    float* __restrict__ h, ushort_t* __restrict__ h_bf,
    int* __restrict__ counts,
    float* __restrict__ Wc, float* __restrict__ bcb,
    ushort_t* __restrict__ Wall_arr, float* __restrict__ Wall_bias,
    ushort_t* __restrict__ wv_arr,
    int O0, int O1, int O2, int N) {
    int b = blockIdx.x, t = threadIdx.x;
    if (b < O0) {
        int idx = b * 256 + t;
        if (idx < N * 64) {
            int n = idx >> 6, c = idx & 63;
            float acc = node_b[c];
#pragma unroll
            for (int j = 0; j < 16; ++j) acc += x[n * 16 + j] * node_W[j * 64 + c];
            h[idx] = acc;
            h_bf[idx] = f2bf(acc);
        }
    } else if (b < O1) {
        int i = (b - O0) * 256 + t;
        if (i < N) counts[i] = 0;
    } else if (b < O2) {
        int tid = (b - O1) * 256 + t;
        if (tid < 2048) {
            int l = tid >> 10, d = (tid >> 7) & 7, j = tid & 127;
            float s = 0.f;
            for (int m = 0; m < 64; ++m) s += edge_W[d * 64 + m] * We[l * 8192 + m * 128 + j];
            Wc[l * 1024 + d * 128 + j] = s;
        } else if (tid < 2048 + 256) {
            int u = tid - 2048;
            int l = u >> 7, j = u & 127;
            float s = be[l * 128 + j];
            for (int m = 0; m < 64; ++m) s += edge_b[m] * We[l * 8192 + m * 128 + j];
            bcb[l * 128 + j] = s;
        }
    } else {
        int tid = (b - O2) * 256 + t;
        if (tid < 2 * 14336) {
            int l = tid / 14336, u = tid % 14336;
            int j = u & 7, ln = (u >> 3) & 63, kch = (u >> 9) & 1, ct = u >> 10;
            int nn = ln & 15, quad = ln >> 4;
            int k = kch * 32 + quad * 8 + j;
            int col = ct * 16 + nn;
            float v = 0.f;
            if (col < 128) {
                // composed 0.125 * (Wq_h Wk_h^T)[k, m]
                int hh = col >> 6, m = col & 63;
                const float* wq = Wq + l * 8192 + k * 128 + hh * 64;
                const float* wk = Wk + l * 8192 + m * 128 + hh * 64;
                float s = 0.f;
                for (int c2 = 0; c2 < 64; ++c2) s += wq[c2] * wk[c2];
                v = 0.125f * s;
            } else if (col < 192) {
                v = Wskip[l * 4096 + k * 64 + (col - 128)];
            }  // cols 192..223: 0 here; combine2 fills 192..209
            Wall_arr[(size_t)l * 14336 + ct * 1024 + kch * 512 + ln * 8 + j] = f2bf(v);
        } else if (tid < 2 * 14336 + 2 * 224) {
            int u = tid - 2 * 14336;
            int l = u / 224, col = u % 224;
            float v = 0.f;
            if (col < 128) {
                int hh = col >> 6, m = col & 63;
                const float* bqp = bq + l * 128 + hh * 64;
                const float* wk = Wk + l * 8192 + m * 128 + hh * 64;
                float s = 0.f;
                for (int c2 = 0; c2 < 64; ++c2) s += bqp[c2] * wk[c2];
                v = 0.125f * s;
            } else if (col < 192) {
                v = bskip[l * 64 + col - 128];
            }
            Wall_bias[l * 224 + col] = v;
        } else if (tid < 2 * 14336 + 2 * 224 + 2 * 8192) {
            // Wv stacked tiles: B[p = h*64+m][c] = Wv[m, h*64+c]
            // flat r = kc*2048 + ct*512 + ln*8 + j
            int u = tid - (2 * 14336 + 2 * 224);
            int l = u >> 13, r = u & 8191;
            int j = r & 7, ln = (r >> 3) & 63, ct = (r >> 9) & 3, kc = r >> 11;
            int quad = ln >> 4, nn = ln & 15;
            int p = kc * 32 + quad * 8 + j;
            int hh = p >> 6, m = p & 63;
            int c2 = ct * 16 + nn;
            wv_arr[(size_t)l * 8192 + r] = f2bf(Wv[l * 8192 + m * 128 + hh * 64 + c2]);
        }
    }
}

// combine2: qc composed columns (ea-dot path, with q·bk folded into bias cols) + cst
__global__ void combine2_kernel(const float* __restrict__ Wq, const float* __restrict__ bq,
                                const float* __restrict__ bk, const float* __restrict__ bv,
                                const float* __restrict__ Wc, const float* __restrict__ bcb,
                                ushort_t* __restrict__ Wall_arr, float* __restrict__ Wall_bias,
                                float* __restrict__ cst) {
    int tid = blockIdx.x * 256 + threadIdx.x;
    if (tid < 2304) {
        int l = tid / 1152, u = tid % 1152, k = u / 18, j = u % 18;
        float s = 0.f;
        if (j < 16) {
            int hh = j >> 3, d = j & 7;
            for (int c = 0; c < 64; ++c)
                s += Wq[l * 8192 + k * 128 + hh * 64 + c] * Wc[l * 1024 + d * 128 + hh * 64 + c];
        } else {
            int hh = j - 16;
            for (int c = 0; c < 64; ++c)
                s += Wq[l * 8192 + k * 128 + hh * 64 + c] *
                     (bcb[l * 128 + hh * 64 + c] + bk[l * 128 + hh * 64 + c]);
        }
        s *= 0.125f;
        int col = 192 + j;
        int ct = col >> 4, nn = col & 15;
        int kch = k >> 5, quad = (k >> 3) & 3, jj = k & 7;
        int ln = quad * 16 + nn;
        Wall_arr[(size_t)l * 14336 + ct * 1024 + kch * 512 + ln * 8 + jj] = f2bf(s);
    } else if (tid < 2304 + 36) {
        int u = tid - 2304;
        int l = u / 18, j = u % 18;
        float s = 0.f;
        if (j < 16) {
            int hh = j >> 3, d = j & 7;
            for (int c = 0; c < 64; ++c)
                s += bq[l * 128 + hh * 64 + c] * Wc[l * 1024 + d * 128 + hh * 64 + c];
        } else {
            int hh = j - 16;
            for (int c = 0; c < 64; ++c)
                s += bq[l * 128 + hh * 64 + c] *
                     (bcb[l * 128 + hh * 64 + c] + bk[l * 128 + hh * 64 + c]);
        }
        Wall_bias[l * 224 + 192 + j] = 0.125f * s;
    } else if (tid < 2304 + 36 + 128) {
        int u = tid - 2340;
        int l = u >> 6, c = u & 63;
        cst[l * 64 + c] = 0.5f * (bv[l * 128 + c] + bv[l * 128 + 64 + c] +
                                  bcb[l * 128 + c] + bcb[l * 128 + 64 + c]);
    }
}

// ---------------- CSR build ----------------

__global__ void csr_count_kernel(const int* __restrict__ dst, int* __restrict__ counts, int E) {
    int e = blockIdx.x * 256 + threadIdx.x;
    if (e < E) atomicAdd(&counts[dst[e]], 1);
}

__global__ void scan1_kernel(const int* __restrict__ counts, int* __restrict__ rowptr,
                             int* __restrict__ bsums, int N) {
    __shared__ int s[256];
    int t = threadIdx.x, i = blockIdx.x * 256 + t;
    int v = (i < N) ? counts[i] : 0;
    s[t] = v;
    __syncthreads();
    for (int d = 1; d < 256; d <<= 1) {
        int x = (t >= d) ? s[t - d] : 0;
        __syncthreads();
        s[t] += x;
        __syncthreads();
    }
    if (i < N) rowptr[i] = s[t] - v;
    if (t == 255) bsums[blockIdx.x] = s[255];
}

__global__ void scan3_kernel(int* __restrict__ rowptr, const int* __restrict__ bsums,
                             int* __restrict__ cursor, int N, int E, int nb) {
    __shared__ int sh[256];
    int t = threadIdx.x;
    int v = (t < nb) ? bsums[t] : 0;
    sh[t] = v;
    __syncthreads();
    for (int d = 1; d < 256; d <<= 1) {
        int x = (t >= d) ? sh[t - d] : 0;
        __syncthreads();
        sh[t] += x;
        __syncthreads();
    }
    int blk = blockIdx.x;
    int offv = (blk == 0) ? 0 : sh[blk - 1];
    int i = blk * 256 + t;
    if (i < N) {
        int r = rowptr[i] + offv;
        rowptr[i] = r;
        cursor[i] = r;
    }
    if (i == 0) rowptr[N] = E;
}

// one 32-B record per edge: [src_off:int | pad:12B | ea bf16x8:16B]
__global__ void csr_fill_kernel(const int* __restrict__ dst, const int* __restrict__ src,
                                const float* __restrict__ edge_attr, int* __restrict__ cursor,
                                char* __restrict__ erec, int E) {
    int e = blockIdx.x * 256 + threadIdx.x;
    if (e < E) {
        int pos = atomicAdd(&cursor[dst[e]], 1);
        float4 a0 = *(const float4*)(edge_attr + (size_t)e * 8);
        float4 a1 = *(const float4*)(edge_attr + (size_t)e * 8 + 4);
        uint4 w1;
        w1.x = (unsigned)f2bf(a0.x) | ((unsigned)f2bf(a0.y) << 16);
        w1.y = (unsigned)f2bf(a0.z) | ((unsigned)f2bf(a0.w) << 16);
        w1.z = (unsigned)f2bf(a1.x) | ((unsigned)f2bf(a1.y) << 16);
        w1.w = (unsigned)f2bf(a1.z) | ((unsigned)f2bf(a1.w) << 16);
        char* rp = erec + (size_t)pos * 32;
        *(uint4*)rp = make_uint4((unsigned)(src[e] * 128), 0u, 0u, 0u);
        *(uint4*)(rp + 16) = w1;
    }
}

// ---------------- fused per-layer kernel: GEMM -> attn (edge-split pairs) -> V-apply --
// 512 threads = 8 waves, 16 nodes per block. Waves (2p, 2p+1) co-own 4 nodes and
// split each node's edge list in half; partials (lsum/hacc/se are edge-additive)
// combine through LDS. Halves the serial gather depth per wave.

__global__ __launch_bounds__(512) void layer_kernel(
    const ushort_t* __restrict__ h_bf,
    const char* __restrict__ erec, const int* __restrict__ rowptr,
    const ushort_t* __restrict__ Wall_arr, const float* __restrict__ Wall_bias,
    const ushort_t* __restrict__ wv_arr, const float* __restrict__ Wc,
    const float* __restrict__ cst,
    float* __restrict__ outbuf, float* __restrict__ part, int N) {
    __shared__ ushort_t qk2_s[16][128];   // composed query, bf16
    __shared__ ushort_t ha_s[16][136];    // normalized hacc, bf16 (pad to 136)
    __shared__ float qc_s[16][20];        // 18 used: qcA(8) qcB(8) qb(2)
    __shared__ float skip_s[16][64];
    __shared__ float sen_s[16][16];
    __shared__ float dw_s[16];
    __shared__ float Wc_s[1024];
    __shared__ float cst_s[64];
    __shared__ float ps[128];
    __shared__ float ph[16][128];         // odd-half hacc partials (f32)
    __shared__ float pse[16][16];         // odd-half se partials
    __shared__ float plsum[16][2];        // odd-half lsum per head
    int t = threadIdx.x;
    int lane = t & 63, wid = t >> 6;
    int n0 = blockIdx.x * 16;
    for (int i = t; i < 1024; i += 512) Wc_s[i] = Wc[i];
    if (t < 64) cst_s[t] = cst[t];

    // ---- Phase 0: GEMM [16x64]@[64x210] from global h_bf into LDS ----
    {
        int quad = lane >> 4, nn16 = lane & 15;
        int nodeA = n0 + nn16; if (nodeA >= N) nodeA = N - 1;
        const ushort_t* apA = h_bf + (size_t)nodeA * 64 + quad * 8;
        short8 aA0 = *(const short8*)apA;
        short8 aA1 = *(const short8*)(apA + 32);
        for (int ct = wid; ct < 14; ct += 8) {
            const ushort_t* bp = Wall_arr + (size_t)ct * 1024 + lane * 8;
            short8 b0 = *(const short8*)bp;
            short8 b1 = *(const short8*)(bp + 512);
            float4v cA = {0.f, 0.f, 0.f, 0.f};
            cA = __builtin_amdgcn_mfma_f32_16x16x32_bf16(aA0, b0, cA, 0, 0, 0);
            cA = __builtin_amdgcn_mfma_f32_16x16x32_bf16(aA1, b1, cA, 0, 0, 0);
            int col = ct * 16 + nn16;
            float bias = Wall_bias[col];
#pragma unroll
            for (int r = 0; r < 4; ++r) {
                float v = cA[r] + bias;
                int ln2 = quad * 4 + r;
                if (col < 128) qk2_s[ln2][col] = f2bf(v);
                else if (col < 192) skip_s[ln2][col - 128] = v;
                else if (col < 210) qc_s[ln2][col - 192] = v;
            }
        }
    }
    __syncthreads();

    // ---- Phase 1: attention; wave pair splits each node's edge list ----
    {
        int grp = lane >> 4, l16 = lane & 15;
        int head = l16 >> 3, l8 = l16 & 7;
        int pairIdx = wid >> 1, halfIdx = wid & 1;
        const char* hbb = (const char*)h_bf;
        int ln = pairIdx * 4 + grp;         // local node 0..15
        int n = n0 + ln;
        bool active = (n < N);
        int nn = active ? n : (N - 1);
        int start = rowptr[nn];
        int deg = active ? (rowptr[nn + 1] - start) : 0;
        int h1cnt = (deg + 1) >> 1;
        int mycnt = halfIdx ? (deg - h1cnt) : h1cnt;
        int mystart = start + (halfIdx ? h1cnt : 0);
        int wdeg = mycnt;
        wdeg = max(wdeg, __shfl_xor(wdeg, 16));
        wdeg = max(wdeg, __shfl_xor(wdeg, 32));

        float lsum = 0.f;
        float hacc[8] = {0.f, 0.f, 0.f, 0.f, 0.f, 0.f, 0.f, 0.f};
        float se[8]   = {0.f, 0.f, 0.f, 0.f, 0.f, 0.f, 0.f, 0.f};

        if (wdeg > 0) {
            uint4 qr = *(const uint4*)&qk2_s[ln][head * 64 + l8 * 8];
            float qk0 = bfu_lo(qr.x), qk1 = bfu_hi(qr.x);
            float qk2f = bfu_lo(qr.y), qk3 = bfu_hi(qr.y);
            float qk4 = bfu_lo(qr.z), qk5 = bfu_hi(qr.z);
            float qk6 = bfu_lo(qr.w), qk7 = bfu_hi(qr.w);
            float4 qcA = *(const float4*)&qc_s[ln][head * 8];
            float4 qcB = *(const float4*)&qc_s[ln][head * 8 + 4];
            float qb = qc_s[ln][16 + head];

            bool dpos = (mycnt > 0);
            int dclamp = dpos ? (mycnt - 1) : 0;
            int base = dpos ? mystart : 0;

            int offL = *(const int*)(erec + (size_t)(base + min(l16, dclamp)) * 32);
            int o0 = __shfl(offL, grp * 16);
            uint4 ca = *(const uint4*)(hbb + (size_t)(unsigned)o0 + l8 * 16);
            uint4 ev = *(const uint4*)(erec + (size_t)base * 32 + 16);

            for (int it = 0; it < wdeg; ++it) {
                int itn = it + 1;
                if ((itn & 15) == 0)
                    offL = *(const int*)(erec + (size_t)(base + min(itn + l16, dclamp)) * 32);
                int itc = min(itn, wdeg - 1);
                int on = __shfl(offL, grp * 16 + (itc & 15));
                uint4 na = *(const uint4*)(hbb + (size_t)(unsigned)on + l8 * 16);
                int gin = base + min(itc, dclamp);
                uint4 fv = *(const uint4*)(erec + (size_t)gin * 32 + 16);

                float h0 = bfu_lo(ca.x), h1 = bfu_hi(ca.x);
                float h2 = bfu_lo(ca.y), h3 = bfu_hi(ca.y);
                float h4 = bfu_lo(ca.z), h5 = bfu_hi(ca.z);
                float h6 = bfu_lo(ca.w), h7 = bfu_hi(ca.w);
                float dt = qk0 * h0 + qk1 * h1 + qk2f * h2 + qk3 * h3
                         + qk4 * h4 + qk5 * h5 + qk6 * h6 + qk7 * h7;
                dt += __shfl_xor(dt, 1);
                dt += __shfl_xor(dt, 2);
                dt += __shfl_xor(dt, 4);
                float ex0 = bfu_lo(ev.x), ex1 = bfu_hi(ev.x);
                float ex2 = bfu_lo(ev.y), ex3 = bfu_hi(ev.y);
                float ex4 = bfu_lo(ev.z), ex5 = bfu_hi(ev.z);
                float ex6 = bfu_lo(ev.w), ex7 = bfu_hi(ev.w);
                float s0 = dt
                         + qcA.x * ex0 + qcA.y * ex1 + qcA.z * ex2 + qcA.w * ex3
                         + qcB.x * ex4 + qcB.y * ex5 + qcB.z * ex6 + qcB.w * ex7
                         + qb;
                float p = (it < mycnt) ? __expf(fmaxf(s0, -60.f)) : 0.f;
                lsum += p;
                hacc[0] += p * h0; hacc[1] += p * h1;
                hacc[2] += p * h2; hacc[3] += p * h3;
                hacc[4] += p * h4; hacc[5] += p * h5;
                hacc[6] += p * h6; hacc[7] += p * h7;
                se[0] += p * ex0; se[1] += p * ex1; se[2] += p * ex2; se[3] += p * ex3;
                se[4] += p * ex4; se[5] += p * ex5; se[6] += p * ex6; se[7] += p * ex7;
                ca = na; ev = fv;
            }
        }

        if (halfIdx == 1) {
#pragma unroll
            for (int j2 = 0; j2 < 8; ++j2) ph[ln][head * 64 + l8 * 8 + j2] = hacc[j2];
            if (l8 == 0) {
#pragma unroll
                for (int m = 0; m < 8; ++m) pse[ln][head * 8 + m] = se[m];
                plsum[ln][head] = lsum;
            }
        }
        __syncthreads();
        if (halfIdx == 0) {
            lsum += plsum[ln][head];
#pragma unroll
            for (int j2 = 0; j2 < 8; ++j2) hacc[j2] += ph[ln][head * 64 + l8 * 8 + j2];
            float inv = (deg > 0) ? (0.5f / lsum) : 0.f;   // 0.5 = head mean
#pragma unroll
            for (int j2 = 0; j2 < 8; ++j2)
                ha_s[ln][head * 64 + l8 * 8 + j2] = f2bf(hacc[j2] * inv);
            if (l8 == 0) {
#pragma unroll
                for (int m = 0; m < 8; ++m)
                    sen_s[ln][head * 8 + m] = (se[m] + pse[ln][head * 8 + m]) * inv;
                if (head == 0) dw_s[ln] = (deg > 0) ? 1.f : 0.f;
            }
        }
    }
    __syncthreads();

    // ---- Phase 2: V-apply MFMA + ep-compose + cst + skip -> outbuf + BN partials ----
    if (wid < 4) {
        int quad = lane >> 4, nn16 = lane & 15;
        int ct = wid;
        float4v c = {0.f, 0.f, 0.f, 0.f};
#pragma unroll
        for (int kc = 0; kc < 4; ++kc) {
            short8 a = *(const short8*)&ha_s[nn16][kc * 32 + quad * 8];
            short8 b = *(const short8*)(wv_arr + kc * 2048 + ct * 512 + lane * 8);
            c = __builtin_amdgcn_mfma_f32_16x16x32_bf16(a, b, c, 0, 0, 0);
        }
        int col = ct * 16 + nn16;
        float sa = 0.f, sq = 0.f;
#pragma unroll
        for (int r = 0; r < 4; ++r) {
            int ln2 = quad * 4 + r;
            int nr = n0 + ln2;
            const float* sp = sen_s[ln2];
            float ep = 0.f;
#pragma unroll
            for (int hh = 0; hh < 2; ++hh)
#pragma unroll
                for (int d = 0; d < 8; ++d)
                    ep += sp[hh * 8 + d] * Wc_s[d * 128 + hh * 64 + col];
            if (nr < N) {
                float val = c[r] + ep + dw_s[ln2] * cst_s[col] + skip_s[ln2][col];
                outbuf[(size_t)nr * 64 + col] = val;
                sa += val;
                sq += val * val;
            }
        }
        sa += __shfl_xor(sa, 16); sa += __shfl_xor(sa, 32);
        sq += __shfl_xor(sq, 16); sq += __shfl_xor(sq, 32);
        if (quad == 0) { ps[col] = sa; ps[64 + col] = sq; }
    }
    __syncthreads();
    if (t < 128) part[(size_t)blockIdx.x * 128 + t] = ps[t];
}

// ---------------- BN reduce + BN apply kernels ----------------

__global__ __launch_bounds__(256) void bnreduce_kernel(const float* __restrict__ part,
                                                       float* __restrict__ bnsums, int nb) {
    int s = blockIdx.x;  // 0..127
    int t = threadIdx.x;
    float a = 0.f;
    for (int b = t; b < nb; b += 256) a += part[(size_t)b * 128 + s];
    __shared__ float sh[256];
    sh[t] = a;
    __syncthreads();
    for (int d = 128; d; d >>= 1) {
        if (t < d) sh[t] += sh[t + d];
        __syncthreads();
    }
    if (t == 0) bnsums[s] = sh[0];
}

// inter-layer BN apply: h update + h_bf for next layer's gather
__global__ __launch_bounds__(256) void bnh_kernel(
    const float* __restrict__ outbuf, const float* __restrict__ bnsums,
    const float* __restrict__ gamma, const float* __restrict__ beta,
    float* __restrict__ h, ushort_t* __restrict__ h_bf, int N) {
    int idx = blockIdx.x * 256 + threadIdx.x;
    if (idx >= N * 64) return;
    int c = idx & 63;
    float invN = 1.f / (float)N;
    float mean = bnsums[c] * invN;
    float var = bnsums[64 + c] * invN - mean * mean;
    float scale = gamma[c] * rsqrtf(var + 1e-5f);
    float shift = beta[c] - mean * scale;
    float o = outbuf[idx] * scale + shift;
    o = (o > 0.f) ? o : 0.01f * o;
    float hn = h[idx] + o;
    h[idx] = hn;
    h_bf[idx] = f2bf(hn);
}

// final BN apply with gate
__global__ __launch_bounds__(256) void bnapply_kernel(
    const float* __restrict__ outbuf, const float* __restrict__ bnsums,
    const float* __restrict__ gamma, const float* __restrict__ beta,
    const float* __restrict__ gate_W, const float* __restrict__ gate_b,
    float* __restrict__ h, float* __restrict__ gatebuf, int N) {
    int idx = blockIdx.x * 256 + threadIdx.x;
    if (idx >= N * 64) return;
    int c = idx & 63, n = idx >> 6;
    float invN = 1.f / (float)N;
    float mean = bnsums[c] * invN;
    float var = bnsums[64 + c] * invN - mean * mean;
    float scale = gamma[c] * rsqrtf(var + 1e-5f);
    float shift = beta[c] - mean * scale;
    float o = outbuf[idx] * scale + shift;
    o = (o > 0.f) ? o : 0.01f * o;
    float hn = h[idx] + o;
    h[idx] = hn;
    float g = hn * gate_W[c];
#pragma unroll
    for (int off = 32; off; off >>= 1) g += __shfl_xor(g, off);
    if (c == 0) gatebuf[n] = g + gate_b[0];
}

// ---------------- pooling (max fused into acc) ----------------

__global__ __launch_bounds__(256) void pool_acc_kernel(
    const float* __restrict__ h, const float* __restrict__ gatebuf,
    const int* __restrict__ batch,
    float* __restrict__ pacc, float* __restrict__ pden, int N) {
    int b = blockIdx.x >> 3, chunk = blockIdx.x & 7;
    int lo = 0, hi = N;
    while (lo < hi) { int mid = (lo + hi) >> 1; if (batch[mid] < b) lo = mid + 1; else hi = mid; }
    int start = lo;
    lo = start; hi = N;
    while (lo < hi) { int mid = (lo + hi) >> 1; if (batch[mid] <= b) lo = mid + 1; else hi = mid; }
    int end = lo;
    int t = threadIdx.x, lane = t & 63, wid = t >> 6;
    __shared__ float sm[4];
    float mx = -1e30f;
    for (int n = start + t; n < end; n += 256) mx = fmaxf(mx, gatebuf[n]);
#pragma unroll
    for (int off = 32; off; off >>= 1) mx = fmaxf(mx, __shfl_xor(mx, off));
    if (lane == 0) sm[wid] = mx;
    __syncthreads();
    float mb = fmaxf(fmaxf(sm[0], sm[1]), fmaxf(sm[2], sm[3]));
    int gwid = chunk * 4 + wid;
    float acc = 0.f, den = 0.f;
    for (int n = start + gwid; n < end; n += 32) {
        float ge = __expf(gatebuf[n] - mb);
        acc += ge * h[(size_t)n * 64 + lane];
        den += ge;
    }
    __shared__ float sacc[4][64];
    __shared__ float sden[4];
    sacc[wid][lane] = acc;
    if (lane == 0) sden[wid] = den;
    __syncthreads();
    if (wid == 0) {
        pacc[(size_t)blockIdx.x * 64 + lane] =
            sacc[0][lane] + sacc[1][lane] + sacc[2][lane] + sacc[3][lane];
        if (lane == 0) pden[blockIdx.x] = sden[0] + sden[1] + sden[2] + sden[3];
    }
}

__global__ void pool_fin_kernel(const float* __restrict__ pacc, const float* __restrict__ pden,
                                const float* __restrict__ out_W, const float* __restrict__ out_b,
                                float* __restrict__ out) {
    int b = blockIdx.x, c = threadIdx.x;
    float pc = 0.f, dv = 0.f;
#pragma unroll
    for (int j = 0; j < 8; ++j) {
        pc += pacc[(size_t)(b * 8 + j) * 64 + c];
        dv += pden[b * 8 + j];
    }
    float s = pc * out_W[c];
#pragma unroll
    for (int off = 32; off; off >>= 1) s += __shfl_xor(s, off);
    if (c == 0) {
        if (dv <= 0.f) dv = 1.f;
        float v = s / dv + out_b[0];
        out[b] = 1.f / (1.f + __expf(-v));
    }
}

// ---------------- host ----------------

extern "C" void kernel_launch(void* const* d_in, const int* in_sizes, int n_in,
                              void* d_out, int out_size, void* d_ws, size_t ws_size,
                              hipStream_t stream) {
    const float* x         = (const float*)d_in[0];
    const float* edge_attr = (const float*)d_in[1];
    const int*   edge_src  = (const int*)d_in[2];
    const int*   edge_dst  = (const int*)d_in[3];
    const int*   batch     = (const int*)d_in[4];
    const float* node_W    = (const float*)d_in[5];
    const float* node_b    = (const float*)d_in[6];
    const float* edge_W    = (const float*)d_in[7];
    const float* edge_b    = (const float*)d_in[8];
    const float* Wq        = (const float*)d_in[9];
    const float* bq        = (const float*)d_in[10];
    const float* Wk        = (const float*)d_in[11];
    const float* bk        = (const float*)d_in[12];
    const float* Wv        = (const float*)d_in[13];
    const float* bv        = (const float*)d_in[14];
    const float* We        = (const float*)d_in[15];
    const float* be        = (const float*)d_in[16];
    const float* Wskip     = (const float*)d_in[17];
    const float* bskip     = (const float*)d_in[18];
    const float* gamma     = (const float*)d_in[19];
    const float* beta      = (const float*)d_in[20];
    const float* gate_W    = (const float*)d_in[21];
    const float* gate_b    = (const float*)d_in[22];
    const float* out_W     = (const float*)d_in[23];
    const float* out_b     = (const float*)d_in[24];
    float* out = (float*)d_out;

    const int N = in_sizes[0] / 16;
    const int E = in_sizes[2];
    const int nbl = (N + 15) / 16;   // layer blocks: 16 nodes per block

    char* ws = (char*)d_ws;
    size_t off = 0;
    auto alloc = [&](size_t bytes) {
        size_t o = off;
        off += (bytes + 255) & ~(size_t)255;
        return o;
    };
    float*    h        = (float*)(ws + alloc((size_t)N * 64 * 4));
    ushort_t* h_bf     = (ushort_t*)(ws + alloc((size_t)N * 64 * 2));
    float*    outbuf   = (float*)(ws + alloc((size_t)N * 64 * 4));
    int*      rowptr   = (int*)(ws + alloc((size_t)(N + 1) * 4));
    int*      cursor   = (int*)(ws + alloc((size_t)N * 4));
    int*      counts   = (int*)(ws + alloc((size_t)N * 4));
    int*      bsums    = (int*)(ws + alloc(1024));
    char*     erec     = (char*)(ws + alloc((size_t)E * 32));
    float*    Wc       = (float*)(ws + alloc(2 * 1024 * 4));
    float*    bcb      = (float*)(ws + alloc(2 * 128 * 4));
    ushort_t* Wall_arr = (ushort_t*)(ws + alloc(2 * 14336 * 2));
    float*    Wall_b   = (float*)(ws + alloc(2 * 224 * 4));
    ushort_t* wv_arr   = (ushort_t*)(ws + alloc(2 * 8192 * 2));
    float*    cst      = (float*)(ws + alloc(2 * 64 * 4));
    float*    bnsums   = (float*)(ws + alloc(128 * 4));
    float*    gatebuf  = (float*)(ws + alloc((size_t)N * 4));
    float*    part     = (float*)(ws + alloc((size_t)nbl * 128 * 4));
    float*    pacc     = (float*)(ws + alloc((size_t)512 * 64 * 4));
    float*    pden     = (float*)(ws + alloc(512 * 4));
    if (off > ws_size) return;

    int O0 = (N * 64 + 255) / 256;
    int O1 = O0 + (N + 255) / 256;
    int O2 = O1 + 9;
    int O3 = O2 + 178;   // 2*14336 + 2*224 + 2*8192 = 45504 -> 178 blocks
    setup_kernel<<<O3, 256, 0, stream>>>(
        x, node_W, node_b, edge_W, edge_b, We, be, Wq, bq, Wk, bk, Wv, bv, Wskip, bskip,
        h, h_bf, counts, Wc, bcb, Wall_arr, Wall_b, wv_arr, O0, O1, O2, N);
    combine2_kernel<<<10, 256, 0, stream>>>(Wq, bq, bk, bv, Wc, bcb, Wall_arr, Wall_b, cst);

    csr_count_kernel<<<(E + 255) / 256, 256, 0, stream>>>(edge_dst, counts, E);
    int nb = (N + 255) / 256;
    scan1_kernel<<<nb, 256, 0, stream>>>(counts, rowptr, bsums, N);
    scan3_kernel<<<nb, 256, 0, stream>>>(rowptr, bsums, cursor, N, E, nb);
    csr_fill_kernel<<<(E + 255) / 256, 256, 0, stream>>>(edge_dst, edge_src, edge_attr,
                                                         cursor, erec, E);

    // layer 0
    layer_kernel<<<nbl, 512, 0, stream>>>(h_bf, erec, rowptr,
                                          Wall_arr, Wall_b, wv_arr, Wc, cst,
                                          outbuf, part, N);
    bnreduce_kernel<<<128, 256, 0, stream>>>(part, bnsums, nbl);
    bnh_kernel<<<(N * 64 + 255) / 256, 256, 0, stream>>>(
        outbuf, bnsums, gamma, beta, h, h_bf, N);

    // layer 1
    layer_kernel<<<nbl, 512, 0, stream>>>(h_bf, erec, rowptr,
                                          Wall_arr + 14336, Wall_b + 224, wv_arr + 8192,
                                          Wc + 1024, cst + 64,
                                          outbuf, part, N);
    bnreduce_kernel<<<128, 256, 0, stream>>>(part, bnsums, nbl);
    bnapply_kernel<<<(N * 64 + 255) / 256, 256, 0, stream>>>(
        outbuf, bnsums, gamma + 64, beta + 64, gate_W, gate_b, h, gatebuf, N);

    pool_acc_kernel<<<512, 256, 0, stream>>>(h, gatebuf, batch, pacc, pden, N);
    pool_fin_kernel<<<64, 64, 0, stream>>>(pacc, pden, out_W, out_b, out);
}

// Round 8
// 329.447 us; speedup vs baseline: 1.0883x; 1.0883x over previous
//
#include <hip/hip_runtime.h>
#include <hip/hip_bf16.h>

typedef unsigned short ushort_t;
typedef __attribute__((ext_vector_type(8))) short short8;
typedef __attribute__((ext_vector_type(4))) float float4v;

__device__ __forceinline__ float bfu_lo(unsigned u) {
    return __uint_as_float(u << 16);
}
__device__ __forceinline__ float bfu_hi(unsigned u) {
    return __uint_as_float(u & 0xffff0000u);
}
__device__ __forceinline__ float bfu_s(ushort_t u) {
    return __uint_as_float(((unsigned)u) << 16);
}
__device__ __forceinline__ ushort_t f2bf(float f) {
    __hip_bfloat16 h = __float2bfloat16(f);
    return *reinterpret_cast<ushort_t*>(&h);
}

// Wall layout per layer: 14 col-tiles (210 cols used), tile = 1024 ushorts:
//   idx = ct*1024 + kch*512 + lane*8 + j   (k = kch*32 + quad*8 + j, col = ct*16 + nn)
// cols: 0..127 qk2 (composed 0.125*Wq·Wk^T) | 128..191 skip | 192..209 qc (composed ea)
// Edge record (32 B, sector-aligned): +0 src byte-offset (int), +16 ea bf16x8.

// ---------------- fused setup ----------------

__global__ __launch_bounds__(256) void setup_kernel(
    const float* __restrict__ x, const float* __restrict__ node_W,
    const float* __restrict__ node_b,
    const float* __restrict__ edge_W, const float* __restrict__ edge_b,
    const float* __restrict__ We, const float* __restrict__ be,
    const float* __restrict__ Wq, const float* __restrict__ bq,
    const float* __restrict__ Wk, const float* __restrict__ bk,
    const float* __restrict__ Wv, const float* __restrict__ bv,
    const float* __restrict__ Wskip, const float* __restrict__ bskip,
    float* __restrict__ h, ushort_t* __restrict__ h_bf,
    int* __restrict__ counts,
    float* __restrict__ Wc, float* __restrict__ bcb,
    ushort_t* __restrict__ Wall_arr, float* __restrict__ Wall_bias,
    ushort_t* __restrict__ wv_arr,
    int O0, int O1, int O2, int N) {
    int b = blockIdx.x, t = threadIdx.x;
    if (b < O0) {
        int idx = b * 256 + t;
        if (idx < N * 64) {
            int n = idx >> 6, c = idx & 63;
            float acc = node_b[c];
#pragma unroll
            for (int j = 0; j < 16; ++j) acc += x[n * 16 + j] * node_W[j * 64 + c];
            h[idx] = acc;
            h_bf[idx] = f2bf(acc);
        }
    } else if (b < O1) {
        int i = (b - O0) * 256 + t;
        if (i < N) counts[i] = 0;
    } else if (b < O2) {
        int tid = (b - O1) * 256 + t;
        if (tid < 2048) {
            int l = tid >> 10, d = (tid >> 7) & 7, j = tid & 127;
            float s = 0.f;
            for (int m = 0; m < 64; ++m) s += edge_W[d * 64 + m] * We[l * 8192 + m * 128 + j];
            Wc[l * 1024 + d * 128 + j] = s;
        } else if (tid < 2048 + 256) {
            int u = tid - 2048;
            int l = u >> 7, j = u & 127;
            float s = be[l * 128 + j];
            for (int m = 0; m < 64; ++m) s += edge_b[m] * We[l * 8192 + m * 128 + j];
            bcb[l * 128 + j] = s;
        }
    } else {
        int tid = (b - O2) * 256 + t;
        if (tid < 2 * 14336) {
            int l = tid / 14336, u = tid % 14336;
            int j = u & 7, ln = (u >> 3) & 63, kch = (u >> 9) & 1, ct = u >> 10;
            int nn = ln & 15, quad = ln >> 4;
            int k = kch * 32 + quad * 8 + j;
            int col = ct * 16 + nn;
            float v = 0.f;
            if (col < 128) {
                // composed 0.125 * (Wq_h Wk_h^T)[k, m]
                int hh = col >> 6, m = col & 63;
                const float* wq = Wq + l * 8192 + k * 128 + hh * 64;
                const float* wk = Wk + l * 8192 + m * 128 + hh * 64;
                float s = 0.f;
                for (int c2 = 0; c2 < 64; ++c2) s += wq[c2] * wk[c2];
                v = 0.125f * s;
            } else if (col < 192) {
                v = Wskip[l * 4096 + k * 64 + (col - 128)];
            }  // cols 192..223: 0 here; combine2 fills 192..209
            Wall_arr[(size_t)l * 14336 + ct * 1024 + kch * 512 + ln * 8 + j] = f2bf(v);
        } else if (tid < 2 * 14336 + 2 * 224) {
            int u = tid - 2 * 14336;
            int l = u / 224, col = u % 224;
            float v = 0.f;
            if (col < 128) {
                int hh = col >> 6, m = col & 63;
                const float* bqp = bq + l * 128 + hh * 64;
                const float* wk = Wk + l * 8192 + m * 128 + hh * 64;
                float s = 0.f;
                for (int c2 = 0; c2 < 64; ++c2) s += bqp[c2] * wk[c2];
                v = 0.125f * s;
            } else if (col < 192) {
                v = bskip[l * 64 + col - 128];
            }
            Wall_bias[l * 224 + col] = v;
        } else if (tid < 2 * 14336 + 2 * 224 + 2 * 8192) {
            // Wv stacked tiles: B[p = h*64+m][c] = Wv[m, h*64+c]
            // flat r = kc*2048 + ct*512 + ln*8 + j
            int u = tid - (2 * 14336 + 2 * 224);
            int l = u >> 13, r = u & 8191;
            int j = r & 7, ln = (r >> 3) & 63, ct = (r >> 9) & 3, kc = r >> 11;
            int quad = ln >> 4, nn = ln & 15;
            int p = kc * 32 + quad * 8 + j;
            int hh = p >> 6, m = p & 63;
            int c2 = ct * 16 + nn;
            wv_arr[(size_t)l * 8192 + r] = f2bf(Wv[l * 8192 + m * 128 + hh * 64 + c2]);
        }
    }
}

// combine2: qc composed columns (ea-dot path, with q·bk folded into bias cols) + cst
__global__ void combine2_kernel(const float* __restrict__ Wq, const float* __restrict__ bq,
                                const float* __restrict__ bk, const float* __restrict__ bv,
                                const float* __restrict__ Wc, const float* __restrict__ bcb,
                                ushort_t* __restrict__ Wall_arr, float* __restrict__ Wall_bias,
                                float* __restrict__ cst) {
    int tid = blockIdx.x * 256 + threadIdx.x;
    if (tid < 2304) {
        int l = tid / 1152, u = tid % 1152, k = u / 18, j = u % 18;
        float s = 0.f;
        if (j < 16) {
            int hh = j >> 3, d = j & 7;
            for (int c = 0; c < 64; ++c)
                s += Wq[l * 8192 + k * 128 + hh * 64 + c] * Wc[l * 1024 + d * 128 + hh * 64 + c];
        } else {
            int hh = j - 16;
            for (int c = 0; c < 64; ++c)
                s += Wq[l * 8192 + k * 128 + hh * 64 + c] *
                     (bcb[l * 128 + hh * 64 + c] + bk[l * 128 + hh * 64 + c]);
        }
        s *= 0.125f;
        int col = 192 + j;
        int ct = col >> 4, nn = col & 15;
        int kch = k >> 5, quad = (k >> 3) & 3, jj = k & 7;
        int ln = quad * 16 + nn;
        Wall_arr[(size_t)l * 14336 + ct * 1024 + kch * 512 + ln * 8 + jj] = f2bf(s);
    } else if (tid < 2304 + 36) {
        int u = tid - 2304;
        int l = u / 18, j = u % 18;
        float s = 0.f;
        if (j < 16) {
            int hh = j >> 3, d = j & 7;
            for (int c = 0; c < 64; ++c)
                s += bq[l * 128 + hh * 64 + c] * Wc[l * 1024 + d * 128 + hh * 64 + c];
        } else {
            int hh = j - 16;
            for (int c = 0; c < 64; ++c)
                s += bq[l * 128 + hh * 64 + c] *
                     (bcb[l * 128 + hh * 64 + c] + bk[l * 128 + hh * 64 + c]);
        }
        Wall_bias[l * 224 + 192 + j] = 0.125f * s;
    } else if (tid < 2304 + 36 + 128) {
        int u = tid - 2340;
        int l = u >> 6, c = u & 63;
        cst[l * 64 + c] = 0.5f * (bv[l * 128 + c] + bv[l * 128 + 64 + c] +
                                  bcb[l * 128 + c] + bcb[l * 128 + 64 + c]);
    }
}

// ---------------- CSR build ----------------

__global__ void csr_count_kernel(const int* __restrict__ dst, int* __restrict__ counts, int E) {
    int e = blockIdx.x * 256 + threadIdx.x;
    if (e < E) atomicAdd(&counts[dst[e]], 1);
}

__global__ void scan1_kernel(const int* __restrict__ counts, int* __restrict__ rowptr,
                             int* __restrict__ bsums, int N) {
    __shared__ int s[256];
    int t = threadIdx.x, i = blockIdx.x * 256 + t;
    int v = (i < N) ? counts[i] : 0;
    s[t] = v;
    __syncthreads();
    for (int d = 1; d < 256; d <<= 1) {
        int x = (t >= d) ? s[t - d] : 0;
        __syncthreads();
        s[t] += x;
        __syncthreads();
    }
    if (i < N) rowptr[i] = s[t] - v;
    if (t == 255) bsums[blockIdx.x] = s[255];
}

__global__ void scan3_kernel(int* __restrict__ rowptr, const int* __restrict__ bsums,
                             int* __restrict__ cursor, int N, int E, int nb) {
    __shared__ int sh[256];
    int t = threadIdx.x;
    int v = (t < nb) ? bsums[t] : 0;
    sh[t] = v;
    __syncthreads();
    for (int d = 1; d < 256; d <<= 1) {
        int x = (t >= d) ? sh[t - d] : 0;
        __syncthreads();
        sh[t] += x;
        __syncthreads();
    }
    int blk = blockIdx.x;
    int offv = (blk == 0) ? 0 : sh[blk - 1];
    int i = blk * 256 + t;
    if (i < N) {
        int r = rowptr[i] + offv;
        rowptr[i] = r;
        cursor[i] = r;
    }
    if (i == 0) rowptr[N] = E;
}

// one 32-B record per edge: [src_off:int | pad:12B | ea bf16x8:16B]
__global__ void csr_fill_kernel(const int* __restrict__ dst, const int* __restrict__ src,
                                const float* __restrict__ edge_attr, int* __restrict__ cursor,
                                char* __restrict__ erec, int E) {
    int e = blockIdx.x * 256 + threadIdx.x;
    if (e < E) {
        int pos = atomicAdd(&cursor[dst[e]], 1);
        float4 a0 = *(const float4*)(edge_attr + (size_t)e * 8);
        float4 a1 = *(const float4*)(edge_attr + (size_t)e * 8 + 4);
        uint4 w1;
        w1.x = (unsigned)f2bf(a0.x) | ((unsigned)f2bf(a0.y) << 16);
        w1.y = (unsigned)f2bf(a0.z) | ((unsigned)f2bf(a0.w) << 16);
        w1.z = (unsigned)f2bf(a1.x) | ((unsigned)f2bf(a1.y) << 16);
        w1.w = (unsigned)f2bf(a1.z) | ((unsigned)f2bf(a1.w) << 16);
        char* rp = erec + (size_t)pos * 32;
        *(uint4*)rp = make_uint4((unsigned)(src[e] * 128), 0u, 0u, 0u);
        *(uint4*)(rp + 16) = w1;
    }
}

// ---------------- fused per-layer kernel: GEMM -> attn -> V-apply ----------------
// 512 threads = 8 waves, 32 nodes per block (round-6 structure).
// Attn loop optimization: ea is distributed per lane (lane l8 owns ea[l8]);
// the qc·ea dot folds into the 8-lane butterfly; se collapses to one scalar/lane.

__global__ __launch_bounds__(512) void layer_kernel(
    const ushort_t* __restrict__ h_bf,
    const char* __restrict__ erec, const int* __restrict__ rowptr,
    const ushort_t* __restrict__ Wall_arr, const float* __restrict__ Wall_bias,
    const ushort_t* __restrict__ wv_arr, const float* __restrict__ Wc,
    const float* __restrict__ cst,
    float* __restrict__ outbuf, float* __restrict__ part, int N) {
    __shared__ ushort_t qk2_s[32][128];   // composed query, bf16
    __shared__ ushort_t ha_s[32][136];    // normalized hacc, bf16 (pad to 136)
    __shared__ float qc_s[32][20];        // 18 used: qc(16) qb(2)
    __shared__ float skip_s[32][64];
    __shared__ float sen_s[32][16];
    __shared__ float dw_s[32];
    __shared__ float Wc_s[1024];
    __shared__ float cst_s[64];
    __shared__ float ps[2][128];
    int t = threadIdx.x;
    int lane = t & 63, wid = t >> 6;
    int n0 = blockIdx.x * 32;
    for (int i = t; i < 1024; i += 512) Wc_s[i] = Wc[i];
    if (t < 64) cst_s[t] = cst[t];

    // ---- Phase 0: GEMM [32x64]@[64x210] from global h_bf into LDS ----
    {
        int quad = lane >> 4, nn16 = lane & 15;
        int nodeA = n0 + nn16;      if (nodeA >= N) nodeA = N - 1;
        int nodeB = n0 + 16 + nn16; if (nodeB >= N) nodeB = N - 1;
        const ushort_t* apA = h_bf + (size_t)nodeA * 64 + quad * 8;
        const ushort_t* apB = h_bf + (size_t)nodeB * 64 + quad * 8;
        short8 aA0 = *(const short8*)apA;
        short8 aA1 = *(const short8*)(apA + 32);
        short8 aB0 = *(const short8*)apB;
        short8 aB1 = *(const short8*)(apB + 32);
        for (int ct = wid; ct < 14; ct += 8) {
            const ushort_t* bp = Wall_arr + (size_t)ct * 1024 + lane * 8;
            short8 b0 = *(const short8*)bp;
            short8 b1 = *(const short8*)(bp + 512);
            float4v cA = {0.f, 0.f, 0.f, 0.f};
            float4v cB = {0.f, 0.f, 0.f, 0.f};
            cA = __builtin_amdgcn_mfma_f32_16x16x32_bf16(aA0, b0, cA, 0, 0, 0);
            cA = __builtin_amdgcn_mfma_f32_16x16x32_bf16(aA1, b1, cA, 0, 0, 0);
            cB = __builtin_amdgcn_mfma_f32_16x16x32_bf16(aB0, b0, cB, 0, 0, 0);
            cB = __builtin_amdgcn_mfma_f32_16x16x32_bf16(aB1, b1, cB, 0, 0, 0);
            int col = ct * 16 + nn16;
            float bias = Wall_bias[col];
#pragma unroll
            for (int g = 0; g < 2; ++g) {
                float4v c = g ? cB : cA;
                int lbase = g * 16 + quad * 4;
#pragma unroll
                for (int r = 0; r < 4; ++r) {
                    float v = c[r] + bias;
                    int ln2 = lbase + r;
                    if (col < 128) qk2_s[ln2][col] = f2bf(v);
                    else if (col < 192) skip_s[ln2][col - 128] = v;
                    else if (col < 210) qc_s[ln2][col - 192] = v;
                }
            }
        }
    }
    __syncthreads();

    // ---- Phase 1: attention (gather h_bf 128B/edge; ea distributed per lane) ----
    {
        int grp = lane >> 4, l16 = lane & 15;
        int head = l16 >> 3, l8 = l16 & 7;
        const char* hbb = (const char*)h_bf;
        int ln = wid * 4 + grp;             // local node 0..31
        int n = n0 + ln;
        bool active = (n < N);
        int nn = active ? n : (N - 1);
        int start = rowptr[nn];
        int deg = active ? (rowptr[nn + 1] - start) : 0;
        int wdeg = deg;
        wdeg = max(wdeg, __shfl_xor(wdeg, 16));
        wdeg = max(wdeg, __shfl_xor(wdeg, 32));

        float lsum = 0.f;
        float se_own = 0.f;
        float hacc[8] = {0.f, 0.f, 0.f, 0.f, 0.f, 0.f, 0.f, 0.f};

        if (wdeg > 0) {
            uint4 qr = *(const uint4*)&qk2_s[ln][head * 64 + l8 * 8];
            float qk0 = bfu_lo(qr.x), qk1 = bfu_hi(qr.x);
            float qk2f = bfu_lo(qr.y), qk3 = bfu_hi(qr.y);
            float qk4 = bfu_lo(qr.z), qk5 = bfu_hi(qr.z);
            float qk6 = bfu_lo(qr.w), qk7 = bfu_hi(qr.w);
            float qcown = qc_s[ln][head * 8 + l8];   // this lane's ea-dot weight
            float qb = qc_s[ln][16 + head];

            bool dpos = (deg > 0);
            int dclamp = dpos ? (deg - 1) : 0;
            int base = dpos ? start : 0;

            int offL = *(const int*)(erec + (size_t)(base + min(l16, dclamp)) * 32);
            int o0 = __shfl(offL, grp * 16);
            uint4 ca = *(const uint4*)(hbb + (size_t)(unsigned)o0 + l8 * 16);
            float eaf = bfu_s(*(const ushort_t*)(erec + (size_t)base * 32 + 16 + l8 * 2));

            for (int it = 0; it < wdeg; ++it) {
                int itn = it + 1;
                if ((itn & 15) == 0)
                    offL = *(const int*)(erec + (size_t)(base + min(itn + l16, dclamp)) * 32);
                int itc = min(itn, wdeg - 1);
                int on = __shfl(offL, grp * 16 + (itc & 15));
                uint4 na = *(const uint4*)(hbb + (size_t)(unsigned)on + l8 * 16);
                int gin = base + min(itc, dclamp);
                float fe = bfu_s(*(const ushort_t*)(erec + (size_t)gin * 32 + 16 + l8 * 2));

                float h0 = bfu_lo(ca.x), h1 = bfu_hi(ca.x);
                float h2 = bfu_lo(ca.y), h3 = bfu_hi(ca.y);
                float h4 = bfu_lo(ca.z), h5 = bfu_hi(ca.z);
                float h6 = bfu_lo(ca.w), h7 = bfu_hi(ca.w);
                float dt = qk0 * h0 + qk1 * h1 + qk2f * h2 + qk3 * h3
                         + qk4 * h4 + qk5 * h5 + qk6 * h6 + qk7 * h7
                         + qcown * eaf;              // ea-dot folded into butterfly
                dt += __shfl_xor(dt, 1);
                dt += __shfl_xor(dt, 2);
                dt += __shfl_xor(dt, 4);
                float s0 = dt + qb;
                float p = (it < deg) ? __expf(fmaxf(s0, -60.f)) : 0.f;
                lsum += p;
                hacc[0] += p * h0; hacc[1] += p * h1;
                hacc[2] += p * h2; hacc[3] += p * h3;
                hacc[4] += p * h4; hacc[5] += p * h5;
                hacc[6] += p * h6; hacc[7] += p * h7;
                se_own += p * eaf;
                ca = na; eaf = fe;
            }
        }

        float inv = (deg > 0) ? (0.5f / lsum) : 0.f;   // 0.5 = head mean
#pragma unroll
        for (int j2 = 0; j2 < 8; ++j2)
            ha_s[ln][head * 64 + l8 * 8 + j2] = f2bf(hacc[j2] * inv);
        sen_s[ln][head * 8 + l8] = se_own * inv;
        if (l16 == 0) dw_s[ln] = (deg > 0) ? 1.f : 0.f;
    }
    __syncthreads();

    // ---- Phase 2: V-apply MFMA + ep-compose + cst + skip -> outbuf + BN partials ----
    {
        int quad = lane >> 4, nn16 = lane & 15;
        int ct = wid & 3, g = wid >> 2;
        float4v c = {0.f, 0.f, 0.f, 0.f};
#pragma unroll
        for (int kc = 0; kc < 4; ++kc) {
            short8 a = *(const short8*)&ha_s[g * 16 + nn16][kc * 32 + quad * 8];
            short8 b = *(const short8*)(wv_arr + kc * 2048 + ct * 512 + lane * 8);
            c = __builtin_amdgcn_mfma_f32_16x16x32_bf16(a, b, c, 0, 0, 0);
        }
        int col = ct * 16 + nn16;
        float sa = 0.f, sq = 0.f;
#pragma unroll
        for (int r = 0; r < 4; ++r) {
            int ln2 = g * 16 + quad * 4 + r;
            int nr = n0 + ln2;
            const float* sp = sen_s[ln2];
            float ep = 0.f;
#pragma unroll
            for (int hh = 0; hh < 2; ++hh)
#pragma unroll
                for (int d = 0; d < 8; ++d)
                    ep += sp[hh * 8 + d] * Wc_s[d * 128 + hh * 64 + col];
            if (nr < N) {
                float val = c[r] + ep + dw_s[ln2] * cst_s[col] + skip_s[ln2][col];
                outbuf[(size_t)nr * 64 + col] = val;
                sa += val;
                sq += val * val;
            }
        }
        sa += __shfl_xor(sa, 16); sa += __shfl_xor(sa, 32);
        sq += __shfl_xor(sq, 16); sq += __shfl_xor(sq, 32);
        if (quad == 0) { ps[g][col] = sa; ps[g][64 + col] = sq; }
    }
    __syncthreads();
    if (t < 128) part[(size_t)blockIdx.x * 128 + t] = ps[0][t] + ps[1][t];
}

// ---------------- BN reduce + BN apply kernels ----------------

__global__ __launch_bounds__(256) void bnreduce_kernel(const float* __restrict__ part,
                                                       float* __restrict__ bnsums, int nb) {
    int s = blockIdx.x;  // 0..127
    int t = threadIdx.x;
    float a = 0.f;
    for (int b = t; b < nb; b += 256) a += part[(size_t)b * 128 + s];
    __shared__ float sh[256];
    sh[t] = a;
    __syncthreads();
    for (int d = 128; d; d >>= 1) {
        if (t < d) sh[t] += sh[t + d];
        __syncthreads();
    }
    if (t == 0) bnsums[s] = sh[0];
}

// inter-layer BN apply: h update + h_bf for next layer's gather
__global__ __launch_bounds__(256) void bnh_kernel(
    const float* __restrict__ outbuf, const float* __restrict__ bnsums,
    const float* __restrict__ gamma, const float* __restrict__ beta,
    float* __restrict__ h, ushort_t* __restrict__ h_bf, int N) {
    int idx = blockIdx.x * 256 + threadIdx.x;
    if (idx >= N * 64) return;
    int c = idx & 63;
    float invN = 1.f / (float)N;
    float mean = bnsums[c] * invN;
    float var = bnsums[64 + c] * invN - mean * mean;
    float scale = gamma[c] * rsqrtf(var + 1e-5f);
    float shift = beta[c] - mean * scale;
    float o = outbuf[idx] * scale + shift;
    o = (o > 0.f) ? o : 0.01f * o;
    float hn = h[idx] + o;
    h[idx] = hn;
    h_bf[idx] = f2bf(hn);
}

// final BN apply with gate
__global__ __launch_bounds__(256) void bnapply_kernel(
    const float* __restrict__ outbuf, const float* __restrict__ bnsums,
    const float* __restrict__ gamma, const float* __restrict__ beta,
    const float* __restrict__ gate_W, const float* __restrict__ gate_b,
    float* __restrict__ h, float* __restrict__ gatebuf, int N) {
    int idx = blockIdx.x * 256 + threadIdx.x;
    if (idx >= N * 64) return;
    int c = idx & 63, n = idx >> 6;
    float invN = 1.f / (float)N;
    float mean = bnsums[c] * invN;
    float var = bnsums[64 + c] * invN - mean * mean;
    float scale = gamma[c] * rsqrtf(var + 1e-5f);
    float shift = beta[c] - mean * scale;
    float o = outbuf[idx] * scale + shift;
    o = (o > 0.f) ? o : 0.01f * o;
    float hn = h[idx] + o;
    h[idx] = hn;
    float g = hn * gate_W[c];
#pragma unroll
    for (int off = 32; off; off >>= 1) g += __shfl_xor(g, off);
    if (c == 0) gatebuf[n] = g + gate_b[0];
}

// ---------------- pooling (max fused into acc) ----------------

__global__ __launch_bounds__(256) void pool_acc_kernel(
    const float* __restrict__ h, const float* __restrict__ gatebuf,
    const int* __restrict__ batch,
    float* __restrict__ pacc, float* __restrict__ pden, int N) {
    int b = blockIdx.x >> 3, chunk = blockIdx.x & 7;
    int lo = 0, hi = N;
    while (lo < hi) { int mid = (lo + hi) >> 1; if (batch[mid] < b) lo = mid + 1; else hi = mid; }
    int start = lo;
    lo = start; hi = N;
    while (lo < hi) { int mid = (lo + hi) >> 1; if (batch[mid] <= b) lo = mid + 1; else hi = mid; }
    int end = lo;
    int t = threadIdx.x, lane = t & 63, wid = t >> 6;
    __shared__ float sm[4];
    float mx = -1e30f;
    for (int n = start + t; n < end; n += 256) mx = fmaxf(mx, gatebuf[n]);
#pragma unroll
    for (int off = 32; off; off >>= 1) mx = fmaxf(mx, __shfl_xor(mx, off));
    if (lane == 0) sm[wid] = mx;
    __syncthreads();
    float mb = fmaxf(fmaxf(sm[0], sm[1]), fmaxf(sm[2], sm[3]));
    int gwid = chunk * 4 + wid;
    float acc = 0.f, den = 0.f;
    for (int n = start + gwid; n < end; n += 32) {
        float ge = __expf(gatebuf[n] - mb);
        acc += ge * h[(size_t)n * 64 + lane];
        den += ge;
    }
    __shared__ float sacc[4][64];
    __shared__ float sden[4];
    sacc[wid][lane] = acc;
    if (lane == 0) sden[wid] = den;
    __syncthreads();
    if (wid == 0) {
        pacc[(size_t)blockIdx.x * 64 + lane] =
            sacc[0][lane] + sacc[1][lane] + sacc[2][lane] + sacc[3][lane];
        if (lane == 0) pden[blockIdx.x] = sden[0] + sden[1] + sden[2] + sden[3];
    }
}

__global__ void pool_fin_kernel(const float* __restrict__ pacc, const float* __restrict__ pden,
                                const float* __restrict__ out_W, const float* __restrict__ out_b,
                                float* __restrict__ out) {
    int b = blockIdx.x, c = threadIdx.x;
    float pc = 0.f, dv = 0.f;
#pragma unroll
    for (int j = 0; j < 8; ++j) {
        pc += pacc[(size_t)(b * 8 + j) * 64 + c];
        dv += pden[b * 8 + j];
    }
    float s = pc * out_W[c];
#pragma unroll
    for (int off = 32; off; off >>= 1) s += __shfl_xor(s, off);
    if (c == 0) {
        if (dv <= 0.f) dv = 1.f;
        float v = s / dv + out_b[0];
        out[b] = 1.f / (1.f + __expf(-v));
    }
}

// ---------------- host ----------------

extern "C" void kernel_launch(void* const* d_in, const int* in_sizes, int n_in,
                              void* d_out, int out_size, void* d_ws, size_t ws_size,
                              hipStream_t stream) {
    const float* x         = (const float*)d_in[0];
    const float* edge_attr = (const float*)d_in[1];
    const int*   edge_src  = (const int*)d_in[2];
    const int*   edge_dst  = (const int*)d_in[3];
    const int*   batch     = (const int*)d_in[4];
    const float* node_W    = (const float*)d_in[5];
    const float* node_b    = (const float*)d_in[6];
    const float* edge_W    = (const float*)d_in[7];
    const float* edge_b    = (const float*)d_in[8];
    const float* Wq        = (const float*)d_in[9];
    const float* bq        = (const float*)d_in[10];
    const float* Wk        = (const float*)d_in[11];
    const float* bk        = (const float*)d_in[12];
    const float* Wv        = (const float*)d_in[13];
    const float* bv        = (const float*)d_in[14];
    const float* We        = (const float*)d_in[15];
    const float* be        = (const float*)d_in[16];
    const float* Wskip     = (const float*)d_in[17];
    const float* bskip     = (const float*)d_in[18];
    const float* gamma     = (const float*)d_in[19];
    const float* beta      = (const float*)d_in[20];
    const float* gate_W    = (const float*)d_in[21];
    const float* gate_b    = (const float*)d_in[22];
    const float* out_W     = (const float*)d_in[23];
    const float* out_b     = (const float*)d_in[24];
    float* out = (float*)d_out;

    const int N = in_sizes[0] / 16;
    const int E = in_sizes[2];
    const int nbl = (N + 31) / 32;   // layer blocks: 32 nodes per block

    char* ws = (char*)d_ws;
    size_t off = 0;
    auto alloc = [&](size_t bytes) {
        size_t o = off;
        off += (bytes + 255) & ~(size_t)255;
        return o;
    };
    float*    h        = (float*)(ws + alloc((size_t)N * 64 * 4));
    ushort_t* h_bf     = (ushort_t*)(ws + alloc((size_t)N * 64 * 2));
    float*    outbuf   = (float*)(ws + alloc((size_t)N * 64 * 4));
    int*      rowptr   = (int*)(ws + alloc((size_t)(N + 1) * 4));
    int*      cursor   = (int*)(ws + alloc((size_t)N * 4));
    int*      counts   = (int*)(ws + alloc((size_t)N * 4));
    int*      bsums    = (int*)(ws + alloc(1024));
    char*     erec     = (char*)(ws + alloc((size_t)E * 32));
    float*    Wc       = (float*)(ws + alloc(2 * 1024 * 4));
    float*    bcb      = (float*)(ws + alloc(2 * 128 * 4));
    ushort_t* Wall_arr = (ushort_t*)(ws + alloc(2 * 14336 * 2));
    float*    Wall_b   = (float*)(ws + alloc(2 * 224 * 4));
    ushort_t* wv_arr   = (ushort_t*)(ws + alloc(2 * 8192 * 2));
    float*    cst      = (float*)(ws + alloc(2 * 64 * 4));
    float*    bnsums   = (float*)(ws + alloc(128 * 4));
    float*    gatebuf  = (float*)(ws + alloc((size_t)N * 4));
    float*    part     = (float*)(ws + alloc((size_t)nbl * 128 * 4));
    float*    pacc     = (float*)(ws + alloc((size_t)512 * 64 * 4));
    float*    pden     = (float*)(ws + alloc(512 * 4));
    if (off > ws_size) return;

    int O0 = (N * 64 + 255) / 256;
    int O1 = O0 + (N + 255) / 256;
    int O2 = O1 + 9;
    int O3 = O2 + 178;   // 2*14336 + 2*224 + 2*8192 = 45504 -> 178 blocks
    setup_kernel<<<O3, 256, 0, stream>>>(
        x, node_W, node_b, edge_W, edge_b, We, be, Wq, bq, Wk, bk, Wv, bv, Wskip, bskip,
        h, h_bf, counts, Wc, bcb, Wall_arr, Wall_b, wv_arr, O0, O1, O2, N);
    combine2_kernel<<<10, 256, 0, stream>>>(Wq, bq, bk, bv, Wc, bcb, Wall_arr, Wall_b, cst);

    csr_count_kernel<<<(E + 255) / 256, 256, 0, stream>>>(edge_dst, counts, E);
    int nb = (N + 255) / 256;
    scan1_kernel<<<nb, 256, 0, stream>>>(counts, rowptr, bsums, N);
    scan3_kernel<<<nb, 256, 0, stream>>>(rowptr, bsums, cursor, N, E, nb);
    csr_fill_kernel<<<(E + 255) / 256, 256, 0, stream>>>(edge_dst, edge_src, edge_attr,
                                                         cursor, erec, E);

    // layer 0
    layer_kernel<<<nbl, 512, 0, stream>>>(h_bf, erec, rowptr,
                                          Wall_arr, Wall_b, wv_arr, Wc, cst,
                                          outbuf, part, N);
    bnreduce_kernel<<<128, 256, 0, stream>>>(part, bnsums, nbl);
    bnh_kernel<<<(N * 64 + 255) / 256, 256, 0, stream>>>(
        outbuf, bnsums, gamma, beta, h, h_bf, N);

    // layer 1
    layer_kernel<<<nbl, 512, 0, stream>>>(h_bf, erec, rowptr,
                                          Wall_arr + 14336, Wall_b + 224, wv_arr + 8192,
                                          Wc + 1024, cst + 64,
                                          outbuf, part, N);
    bnreduce_kernel<<<128, 256, 0, stream>>>(part, bnsums, nbl);
    bnapply_kernel<<<(N * 64 + 255) / 256, 256, 0, stream>>>(
        outbuf, bnsums, gamma + 64, beta + 64, gate_W, gate_b, h, gatebuf, N);

    pool_acc_kernel<<<512, 256, 0, stream>>>(h, gatebuf, batch, pacc, pden, N);
    pool_fin_kernel<<<64, 64, 0, stream>>>(pacc, pden, out_W, out_b, out);
}

// Round 9
// 324.952 us; speedup vs baseline: 1.1034x; 1.0138x over previous
//
#include <hip/hip_runtime.h>
#include <hip/hip_bf16.h>

typedef unsigned short ushort_t;
typedef __attribute__((ext_vector_type(8))) short short8;
typedef __attribute__((ext_vector_type(4))) float float4v;

__device__ __forceinline__ float bfu_lo(unsigned u) {
    return __uint_as_float(u << 16);
}
__device__ __forceinline__ float bfu_hi(unsigned u) {
    return __uint_as_float(u & 0xffff0000u);
}
__device__ __forceinline__ float bfu_s(ushort_t u) {
    return __uint_as_float(((unsigned)u) << 16);
}
__device__ __forceinline__ ushort_t f2bf(float f) {
    __hip_bfloat16 h = __float2bfloat16(f);
    return *reinterpret_cast<ushort_t*>(&h);
}

// Wall layout per layer: 14 col-tiles (210 cols used), tile = 1024 ushorts:
//   idx = ct*1024 + kch*512 + lane*8 + j   (k = kch*32 + quad*8 + j, col = ct*16 + nn)
// cols: 0..127 qk2 (composed 0.125*Wq·Wk^T) | 128..191 skip | 192..209 qc (composed ea)
// Edge record (32 B, sector-aligned): +0 src byte-offset (int), +16 ea bf16x8.

// ---------------- fused setup ----------------

__global__ __launch_bounds__(256) void setup_kernel(
    const float* __restrict__ x, const float* __restrict__ node_W,
    const float* __restrict__ node_b,
    const float* __restrict__ edge_W, const float* __restrict__ edge_b,
    const float* __restrict__ We, const float* __restrict__ be,
    const float* __restrict__ Wq, const float* __restrict__ bq,
    const float* __restrict__ Wk, const float* __restrict__ bk,
    const float* __restrict__ Wv, const float* __restrict__ bv,
    const float* __restrict__ Wskip, const float* __restrict__ bskip,
    float* __restrict__ h, ushort_t* __restrict__ h_bf,
    int* __restrict__ counts,
    float* __restrict__ Wc, float* __restrict__ bcb,
    ushort_t* __restrict__ Wall_arr, float* __restrict__ Wall_bias,
    ushort_t* __restrict__ wv_arr,
    int O0, int O1, int O2, int N) {
    int b = blockIdx.x, t = threadIdx.x;
    if (b < O0) {
        int idx = b * 256 + t;
        if (idx < N * 64) {
            int n = idx >> 6, c = idx & 63;
            float acc = node_b[c];
#pragma unroll
            for (int j = 0; j < 16; ++j) acc += x[n * 16 + j] * node_W[j * 64 + c];
            h[idx] = acc;
            h_bf[idx] = f2bf(acc);
        }
    } else if (b < O1) {
        int i = (b - O0) * 256 + t;
        if (i < N) counts[i] = 0;
    } else if (b < O2) {
        int tid = (b - O1) * 256 + t;
        if (tid < 2048) {
            int l = tid >> 10, d = (tid >> 7) & 7, j = tid & 127;
            float s = 0.f;
            for (int m = 0; m < 64; ++m) s += edge_W[d * 64 + m] * We[l * 8192 + m * 128 + j];
            Wc[l * 1024 + d * 128 + j] = s;
        } else if (tid < 2048 + 256) {
            int u = tid - 2048;
            int l = u >> 7, j = u & 127;
            float s = be[l * 128 + j];
            for (int m = 0; m < 64; ++m) s += edge_b[m] * We[l * 8192 + m * 128 + j];
            bcb[l * 128 + j] = s;
        }
    } else {
        int tid = (b - O2) * 256 + t;
        if (tid < 2 * 14336) {
            int l = tid / 14336, u = tid % 14336;
            int j = u & 7, ln = (u >> 3) & 63, kch = (u >> 9) & 1, ct = u >> 10;
            int nn = ln & 15, quad = ln >> 4;
            int k = kch * 32 + quad * 8 + j;
            int col = ct * 16 + nn;
            float v = 0.f;
            if (col < 128) {
                // composed 0.125 * (Wq_h Wk_h^T)[k, m]
                int hh = col >> 6, m = col & 63;
                const float* wq = Wq + l * 8192 + k * 128 + hh * 64;
                const float* wk = Wk + l * 8192 + m * 128 + hh * 64;
                float s = 0.f;
                for (int c2 = 0; c2 < 64; ++c2) s += wq[c2] * wk[c2];
                v = 0.125f * s;
            } else if (col < 192) {
                v = Wskip[l * 4096 + k * 64 + (col - 128)];
            }  // cols 192..223: 0 here; combine2 fills 192..209
            Wall_arr[(size_t)l * 14336 + ct * 1024 + kch * 512 + ln * 8 + j] = f2bf(v);
        } else if (tid < 2 * 14336 + 2 * 224) {
            int u = tid - 2 * 14336;
            int l = u / 224, col = u % 224;
            float v = 0.f;
            if (col < 128) {
                int hh = col >> 6, m = col & 63;
                const float* bqp = bq + l * 128 + hh * 64;
                const float* wk = Wk + l * 8192 + m * 128 + hh * 64;
                float s = 0.f;
                for (int c2 = 0; c2 < 64; ++c2) s += bqp[c2] * wk[c2];
                v = 0.125f * s;
            } else if (col < 192) {
                v = bskip[l * 64 + col - 128];
            }
            Wall_bias[l * 224 + col] = v;
        } else if (tid < 2 * 14336 + 2 * 224 + 2 * 8192) {
            // Wv stacked tiles: B[p = h*64+m][c] = Wv[m, h*64+c]
            // flat r = kc*2048 + ct*512 + ln*8 + j
            int u = tid - (2 * 14336 + 2 * 224);
            int l = u >> 13, r = u & 8191;
            int j = r & 7, ln = (r >> 3) & 63, ct = (r >> 9) & 3, kc = r >> 11;
            int quad = ln >> 4, nn = ln & 15;
            int p = kc * 32 + quad * 8 + j;
            int hh = p >> 6, m = p & 63;
            int c2 = ct * 16 + nn;
            wv_arr[(size_t)l * 8192 + r] = f2bf(Wv[l * 8192 + m * 128 + hh * 64 + c2]);
        }
    }
}

// combine2: qc composed columns (ea-dot path, with q·bk folded into bias cols) + cst
__global__ void combine2_kernel(const float* __restrict__ Wq, const float* __restrict__ bq,
                                const float* __restrict__ bk, const float* __restrict__ bv,
                                const float* __restrict__ Wc, const float* __restrict__ bcb,
                                ushort_t* __restrict__ Wall_arr, float* __restrict__ Wall_bias,
                                float* __restrict__ cst) {
    int tid = blockIdx.x * 256 + threadIdx.x;
    if (tid < 2304) {
        int l = tid / 1152, u = tid % 1152, k = u / 18, j = u % 18;
        float s = 0.f;
        if (j < 16) {
            int hh = j >> 3, d = j & 7;
            for (int c = 0; c < 64; ++c)
                s += Wq[l * 8192 + k * 128 + hh * 64 + c] * Wc[l * 1024 + d * 128 + hh * 64 + c];
        } else {
            int hh = j - 16;
            for (int c = 0; c < 64; ++c)
                s += Wq[l * 8192 + k * 128 + hh * 64 + c] *
                     (bcb[l * 128 + hh * 64 + c] + bk[l * 128 + hh * 64 + c]);
        }
        s *= 0.125f;
        int col = 192 + j;
        int ct = col >> 4, nn = col & 15;
        int kch = k >> 5, quad = (k >> 3) & 3, jj = k & 7;
        int ln = quad * 16 + nn;
        Wall_arr[(size_t)l * 14336 + ct * 1024 + kch * 512 + ln * 8 + jj] = f2bf(s);
    } else if (tid < 2304 + 36) {
        int u = tid - 2304;
        int l = u / 18, j = u % 18;
        float s = 0.f;
        if (j < 16) {
            int hh = j >> 3, d = j & 7;
            for (int c = 0; c < 64; ++c)
                s += bq[l * 128 + hh * 64 + c] * Wc[l * 1024 + d * 128 + hh * 64 + c];
        } else {
            int hh = j - 16;
            for (int c = 0; c < 64; ++c)
                s += bq[l * 128 + hh * 64 + c] *
                     (bcb[l * 128 + hh * 64 + c] + bk[l * 128 + hh * 64 + c]);
        }
        Wall_bias[l * 224 + 192 + j] = 0.125f * s;
    } else if (tid < 2304 + 36 + 128) {
        int u = tid - 2340;
        int l = u >> 6, c = u & 63;
        cst[l * 64 + c] = 0.5f * (bv[l * 128 + c] + bv[l * 128 + 64 + c] +
                                  bcb[l * 128 + c] + bcb[l * 128 + 64 + c]);
    }
}

// ---------------- CSR build ----------------

__global__ void csr_count_kernel(const int* __restrict__ dst, int* __restrict__ counts, int E) {
    int e = blockIdx.x * 256 + threadIdx.x;
    if (e < E) atomicAdd(&counts[dst[e]], 1);
}

__global__ void scan1_kernel(const int* __restrict__ counts, int* __restrict__ rowptr,
                             int* __restrict__ bsums, int N) {
    __shared__ int s[256];
    int t = threadIdx.x, i = blockIdx.x * 256 + t;
    int v = (i < N) ? counts[i] : 0;
    s[t] = v;
    __syncthreads();
    for (int d = 1; d < 256; d <<= 1) {
        int x = (t >= d) ? s[t - d] : 0;
        __syncthreads();
        s[t] += x;
        __syncthreads();
    }
    if (i < N) rowptr[i] = s[t] - v;
    if (t == 255) bsums[blockIdx.x] = s[255];
}

__global__ void scan3_kernel(int* __restrict__ rowptr, const int* __restrict__ bsums,
                             int* __restrict__ cursor, int N, int E, int nb) {
    __shared__ int sh[256];
    int t = threadIdx.x;
    int v = (t < nb) ? bsums[t] : 0;
    sh[t] = v;
    __syncthreads();
    for (int d = 1; d < 256; d <<= 1) {
        int x = (t >= d) ? sh[t - d] : 0;
        __syncthreads();
        sh[t] += x;
        __syncthreads();
    }
    int blk = blockIdx.x;
    int offv = (blk == 0) ? 0 : sh[blk - 1];
    int i = blk * 256 + t;
    if (i < N) {
        int r = rowptr[i] + offv;
        rowptr[i] = r;
        cursor[i] = r;
    }
    if (i == 0) rowptr[N] = E;
}

// one 32-B record per edge: [src_off:int | pad:12B | ea bf16x8:16B]
__global__ void csr_fill_kernel(const int* __restrict__ dst, const int* __restrict__ src,
                                const float* __restrict__ edge_attr, int* __restrict__ cursor,
                                char* __restrict__ erec, int E) {
    int e = blockIdx.x * 256 + threadIdx.x;
    if (e < E) {
        int pos = atomicAdd(&cursor[dst[e]], 1);
        float4 a0 = *(const float4*)(edge_attr + (size_t)e * 8);
        float4 a1 = *(const float4*)(edge_attr + (size_t)e * 8 + 4);
        uint4 w1;
        w1.x = (unsigned)f2bf(a0.x) | ((unsigned)f2bf(a0.y) << 16);
        w1.y = (unsigned)f2bf(a0.z) | ((unsigned)f2bf(a0.w) << 16);
        w1.z = (unsigned)f2bf(a1.x) | ((unsigned)f2bf(a1.y) << 16);
        w1.w = (unsigned)f2bf(a1.z) | ((unsigned)f2bf(a1.w) << 16);
        char* rp = erec + (size_t)pos * 32;
        *(uint4*)rp = make_uint4((unsigned)(src[e] * 128), 0u, 0u, 0u);
        *(uint4*)(rp + 16) = w1;
    }
}

// ---------------- fused per-layer kernel: GEMM -> attn -> V-apply ----------------
// 512 threads = 8 waves, 32 nodes per block (round-6 structure).
// Round-8: ea distributed per lane. Round-9: in-block degree-sorted wave
// assignment (waves get degree-similar node quartets; bit-identical output)
// + depth-2 gather pipeline (2 outstanding gathers per 16-lane group).

__global__ __launch_bounds__(512) void layer_kernel(
    const ushort_t* __restrict__ h_bf,
    const char* __restrict__ erec, const int* __restrict__ rowptr,
    const ushort_t* __restrict__ Wall_arr, const float* __restrict__ Wall_bias,
    const ushort_t* __restrict__ wv_arr, const float* __restrict__ Wc,
    const float* __restrict__ cst,
    float* __restrict__ outbuf, float* __restrict__ part, int N) {
    __shared__ ushort_t qk2_s[32][128];   // composed query, bf16
    __shared__ ushort_t ha_s[32][136];    // normalized hacc, bf16 (pad to 136)
    __shared__ float qc_s[32][20];        // 18 used: qc(16) qb(2)
    __shared__ float skip_s[32][64];
    __shared__ float sen_s[32][16];
    __shared__ float dw_s[32];
    __shared__ float Wc_s[1024];
    __shared__ float cst_s[64];
    __shared__ float ps[2][128];
    __shared__ int perm_s[32];            // degree-rank -> local node slot
    int t = threadIdx.x;
    int lane = t & 63, wid = t >> 6;
    int n0 = blockIdx.x * 32;
    for (int i = t; i < 1024; i += 512) Wc_s[i] = Wc[i];
    if (t < 64) cst_s[t] = cst[t];

    // ---- Phase 0: GEMM [32x64]@[64x210] from global h_bf into LDS ----
    {
        int quad = lane >> 4, nn16 = lane & 15;
        int nodeA = n0 + nn16;      if (nodeA >= N) nodeA = N - 1;
        int nodeB = n0 + 16 + nn16; if (nodeB >= N) nodeB = N - 1;
        const ushort_t* apA = h_bf + (size_t)nodeA * 64 + quad * 8;
        const ushort_t* apB = h_bf + (size_t)nodeB * 64 + quad * 8;
        short8 aA0 = *(const short8*)apA;
        short8 aA1 = *(const short8*)(apA + 32);
        short8 aB0 = *(const short8*)apB;
        short8 aB1 = *(const short8*)(apB + 32);
        for (int ct = wid; ct < 14; ct += 8) {
            const ushort_t* bp = Wall_arr + (size_t)ct * 1024 + lane * 8;
            short8 b0 = *(const short8*)bp;
            short8 b1 = *(const short8*)(bp + 512);
            float4v cA = {0.f, 0.f, 0.f, 0.f};
            float4v cB = {0.f, 0.f, 0.f, 0.f};
            cA = __builtin_amdgcn_mfma_f32_16x16x32_bf16(aA0, b0, cA, 0, 0, 0);
            cA = __builtin_amdgcn_mfma_f32_16x16x32_bf16(aA1, b1, cA, 0, 0, 0);
            cB = __builtin_amdgcn_mfma_f32_16x16x32_bf16(aB0, b0, cB, 0, 0, 0);
            cB = __builtin_amdgcn_mfma_f32_16x16x32_bf16(aB1, b1, cB, 0, 0, 0);
            int col = ct * 16 + nn16;
            float bias = Wall_bias[col];
#pragma unroll
            for (int g = 0; g < 2; ++g) {
                float4v c = g ? cB : cA;
                int lbase = g * 16 + quad * 4;
#pragma unroll
                for (int r = 0; r < 4; ++r) {
                    float v = c[r] + bias;
                    int ln2 = lbase + r;
                    if (col < 128) qk2_s[ln2][col] = f2bf(v);
                    else if (col < 192) skip_s[ln2][col - 128] = v;
                    else if (col < 210) qc_s[ln2][col - 192] = v;
                }
            }
        }
    }
    __syncthreads();

    // ---- Degree-rank the 32 nodes (wave 0; shfl-based rank sort) ----
    if (t < 32) {
        int nc = n0 + t;
        int d = (nc < N) ? (rowptr[nc + 1] - rowptr[nc]) : 0;
        int r = 0;
#pragma unroll
        for (int m = 0; m < 32; ++m) {
            int dm = __shfl(d, m);
            r += (dm > d || (dm == d && m < t)) ? 1 : 0;
        }
        perm_s[r] = t;   // rank r -> original slot t (descending degree)
    }
    __syncthreads();

    // ---- Phase 1: attention (gather h_bf 128B/edge; depth-2 pipeline) ----
    {
        int grp = lane >> 4, l16 = lane & 15;
        int head = l16 >> 3, l8 = l16 & 7;
        const char* hbb = (const char*)h_bf;
        int ln = perm_s[wid * 4 + grp];     // degree-sorted local node 0..31
        int n = n0 + ln;
        bool active = (n < N);
        int nn = active ? n : (N - 1);
        int start = rowptr[nn];
        int deg = active ? (rowptr[nn + 1] - start) : 0;
        int wdeg = deg;
        wdeg = max(wdeg, __shfl_xor(wdeg, 16));
        wdeg = max(wdeg, __shfl_xor(wdeg, 32));

        float lsum = 0.f;
        float se_own = 0.f;
        float hacc[8] = {0.f, 0.f, 0.f, 0.f, 0.f, 0.f, 0.f, 0.f};

        if (wdeg > 0) {
            uint4 qr = *(const uint4*)&qk2_s[ln][head * 64 + l8 * 8];
            float qk0 = bfu_lo(qr.x), qk1 = bfu_hi(qr.x);
            float qk2f = bfu_lo(qr.y), qk3 = bfu_hi(qr.y);
            float qk4 = bfu_lo(qr.z), qk5 = bfu_hi(qr.z);
            float qk6 = bfu_lo(qr.w), qk7 = bfu_hi(qr.w);
            float qcown = qc_s[ln][head * 8 + l8];   // this lane's ea-dot weight
            float qb = qc_s[ln][16 + head];

            bool dpos = (deg > 0);
            int dclamp = dpos ? (deg - 1) : 0;
            int base = dpos ? start : 0;

            // 16-edge offset window (each slot pre-clamped to dclamp)
            int offL = *(const int*)(erec + (size_t)(base + min(l16, dclamp)) * 32);
            int o0 = __shfl(offL, grp * 16);
            uint4 ca0 = *(const uint4*)(hbb + (size_t)(unsigned)o0 + l8 * 16);
            float ea0 = bfu_s(*(const ushort_t*)(erec + (size_t)base * 32 + 16 + l8 * 2));
            int q1 = min(1, wdeg - 1);
            int o1 = __shfl(offL, grp * 16 + q1);
            uint4 ca1 = *(const uint4*)(hbb + (size_t)(unsigned)o1 + l8 * 16);
            int g1 = base + min(q1, dclamp);
            float ea1 = bfu_s(*(const ushort_t*)(erec + (size_t)g1 * 32 + 16 + l8 * 2));

            for (int it = 0; it < wdeg; ++it) {
                int p2 = it + 2;
                if ((p2 & 15) == 0 && p2 < wdeg)
                    offL = *(const int*)(erec + (size_t)(base + min(p2 + l16, dclamp)) * 32);
                int q2 = min(p2, wdeg - 1);
                int on = __shfl(offL, grp * 16 + (q2 & 15));
                uint4 ca2 = *(const uint4*)(hbb + (size_t)(unsigned)on + l8 * 16);
                int g2 = base + min(q2, dclamp);
                float ea2 = bfu_s(*(const ushort_t*)(erec + (size_t)g2 * 32 + 16 + l8 * 2));

                float h0 = bfu_lo(ca0.x), h1 = bfu_hi(ca0.x);
                float h2 = bfu_lo(ca0.y), h3 = bfu_hi(ca0.y);
                float h4 = bfu_lo(ca0.z), h5 = bfu_hi(ca0.z);
                float h6 = bfu_lo(ca0.w), h7 = bfu_hi(ca0.w);
                float dt = qk0 * h0 + qk1 * h1 + qk2f * h2 + qk3 * h3
                         + qk4 * h4 + qk5 * h5 + qk6 * h6 + qk7 * h7
                         + qcown * ea0;               // ea-dot folded into butterfly
                dt += __shfl_xor(dt, 1);
                dt += __shfl_xor(dt, 2);
                dt += __shfl_xor(dt, 4);
                float s0 = dt + qb;
                float p = (it < deg) ? __expf(fmaxf(s0, -60.f)) : 0.f;
                lsum += p;
                hacc[0] += p * h0; hacc[1] += p * h1;
                hacc[2] += p * h2; hacc[3] += p * h3;
                hacc[4] += p * h4; hacc[5] += p * h5;
                hacc[6] += p * h6; hacc[7] += p * h7;
                se_own += p * ea0;
                ca0 = ca1; ea0 = ea1;
                ca1 = ca2; ea1 = ea2;
            }
        }

        float inv = (deg > 0) ? (0.5f / lsum) : 0.f;   // 0.5 = head mean
#pragma unroll
        for (int j2 = 0; j2 < 8; ++j2)
            ha_s[ln][head * 64 + l8 * 8 + j2] = f2bf(hacc[j2] * inv);
        sen_s[ln][head * 8 + l8] = se_own * inv;
        if (l16 == 0) dw_s[ln] = (deg > 0) ? 1.f : 0.f;
    }
    __syncthreads();

    // ---- Phase 2: V-apply MFMA + ep-compose + cst + skip -> outbuf + BN partials ----
    {
        int quad = lane >> 4, nn16 = lane & 15;
        int ct = wid & 3, g = wid >> 2;
        float4v c = {0.f, 0.f, 0.f, 0.f};
#pragma unroll
        for (int kc = 0; kc < 4; ++kc) {
            short8 a = *(const short8*)&ha_s[g * 16 + nn16][kc * 32 + quad * 8];
            short8 b = *(const short8*)(wv_arr + kc * 2048 + ct * 512 + lane * 8);
            c = __builtin_amdgcn_mfma_f32_16x16x32_bf16(a, b, c, 0, 0, 0);
        }
        int col = ct * 16 + nn16;
        float sa = 0.f, sq = 0.f;
#pragma unroll
        for (int r = 0; r < 4; ++r) {
            int ln2 = g * 16 + quad * 4 + r;
            int nr = n0 + ln2;
            const float* sp = sen_s[ln2];
            float ep = 0.f;
#pragma unroll
            for (int hh = 0; hh < 2; ++hh)
#pragma unroll
                for (int d = 0; d < 8; ++d)
                    ep += sp[hh * 8 + d] * Wc_s[d * 128 + hh * 64 + col];
            if (nr < N) {
                float val = c[r] + ep + dw_s[ln2] * cst_s[col] + skip_s[ln2][col];
                outbuf[(size_t)nr * 64 + col] = val;
                sa += val;
                sq += val * val;
            }
        }
        sa += __shfl_xor(sa, 16); sa += __shfl_xor(sa, 32);
        sq += __shfl_xor(sq, 16); sq += __shfl_xor(sq, 32);
        if (quad == 0) { ps[g][col] = sa; ps[g][64 + col] = sq; }
    }
    __syncthreads();
    if (t < 128) part[(size_t)blockIdx.x * 128 + t] = ps[0][t] + ps[1][t];
}

// ---------------- BN reduce + BN apply kernels ----------------

__global__ __launch_bounds__(256) void bnreduce_kernel(const float* __restrict__ part,
                                                       float* __restrict__ bnsums, int nb) {
    int s = blockIdx.x;  // 0..127
    int t = threadIdx.x;
    float a = 0.f;
    for (int b = t; b < nb; b += 256) a += part[(size_t)b * 128 + s];
    __shared__ float sh[256];
    sh[t] = a;
    __syncthreads();
    for (int d = 128; d; d >>= 1) {
        if (t < d) sh[t] += sh[t + d];
        __syncthreads();
    }
    if (t == 0) bnsums[s] = sh[0];
}

// inter-layer BN apply: h update + h_bf for next layer's gather
__global__ __launch_bounds__(256) void bnh_kernel(
    const float* __restrict__ outbuf, const float* __restrict__ bnsums,
    const float* __restrict__ gamma, const float* __restrict__ beta,
    float* __restrict__ h, ushort_t* __restrict__ h_bf, int N) {
    int idx = blockIdx.x * 256 + threadIdx.x;
    if (idx >= N * 64) return;
    int c = idx & 63;
    float invN = 1.f / (float)N;
    float mean = bnsums[c] * invN;
    float var = bnsums[64 + c] * invN - mean * mean;
    float scale = gamma[c] * rsqrtf(var + 1e-5f);
    float shift = beta[c] - mean * scale;
    float o = outbuf[idx] * scale + shift;
    o = (o > 0.f) ? o : 0.01f * o;
    float hn = h[idx] + o;
    h[idx] = hn;
    h_bf[idx] = f2bf(hn);
}

// final BN apply with gate
__global__ __launch_bounds__(256) void bnapply_kernel(
    const float* __restrict__ outbuf, const float* __restrict__ bnsums,
    const float* __restrict__ gamma, const float* __restrict__ beta,
    const float* __restrict__ gate_W, const float* __restrict__ gate_b,
    float* __restrict__ h, float* __restrict__ gatebuf, int N) {
    int idx = blockIdx.x * 256 + threadIdx.x;
    if (idx >= N * 64) return;
    int c = idx & 63, n = idx >> 6;
    float invN = 1.f / (float)N;
    float mean = bnsums[c] * invN;
    float var = bnsums[64 + c] * invN - mean * mean;
    float scale = gamma[c] * rsqrtf(var + 1e-5f);
    float shift = beta[c] - mean * scale;
    float o = outbuf[idx] * scale + shift;
    o = (o > 0.f) ? o : 0.01f * o;
    float hn = h[idx] + o;
    h[idx] = hn;
    float g = hn * gate_W[c];
#pragma unroll
    for (int off = 32; off; off >>= 1) g += __shfl_xor(g, off);
    if (c == 0) gatebuf[n] = g + gate_b[0];
}

// ---------------- pooling (max fused into acc) ----------------

__global__ __launch_bounds__(256) void pool_acc_kernel(
    const float* __restrict__ h, const float* __restrict__ gatebuf,
    const int* __restrict__ batch,
    float* __restrict__ pacc, float* __restrict__ pden, int N) {
    int b = blockIdx.x >> 3, chunk = blockIdx.x & 7;
    int lo = 0, hi = N;
    while (lo < hi) { int mid = (lo + hi) >> 1; if (batch[mid] < b) lo = mid + 1; else hi = mid; }
    int start = lo;
    lo = start; hi = N;
    while (lo < hi) { int mid = (lo + hi) >> 1; if (batch[mid] <= b) lo = mid + 1; else hi = mid; }
    int end = lo;
    int t = threadIdx.x, lane = t & 63, wid = t >> 6;
    __shared__ float sm[4];
    float mx = -1e30f;
    for (int n = start + t; n < end; n += 256) mx = fmaxf(mx, gatebuf[n]);
#pragma unroll
    for (int off = 32; off; off >>= 1) mx = fmaxf(mx, __shfl_xor(mx, off));
    if (lane == 0) sm[wid] = mx;
    __syncthreads();
    float mb = fmaxf(fmaxf(sm[0], sm[1]), fmaxf(sm[2], sm[3]));
    int gwid = chunk * 4 + wid;
    float acc = 0.f, den = 0.f;
    for (int n = start + gwid; n < end; n += 32) {
        float ge = __expf(gatebuf[n] - mb);
        acc += ge * h[(size_t)n * 64 + lane];
        den += ge;
    }
    __shared__ float sacc[4][64];
    __shared__ float sden[4];
    sacc[wid][lane] = acc;
    if (lane == 0) sden[wid] = den;
    __syncthreads();
    if (wid == 0) {
        pacc[(size_t)blockIdx.x * 64 + lane] =
            sacc[0][lane] + sacc[1][lane] + sacc[2][lane] + sacc[3][lane];
        if (lane == 0) pden[blockIdx.x] = sden[0] + sden[1] + sden[2] + sden[3];
    }
}

__global__ void pool_fin_kernel(const float* __restrict__ pacc, const float* __restrict__ pden,
                                const float* __restrict__ out_W, const float* __restrict__ out_b,
                                float* __restrict__ out) {
    int b = blockIdx.x, c = threadIdx.x;
    float pc = 0.f, dv = 0.f;
#pragma unroll
    for (int j = 0; j < 8; ++j) {
        pc += pacc[(size_t)(b * 8 + j) * 64 + c];
        dv += pden[b * 8 + j];
    }
    float s = pc * out_W[c];
#pragma unroll
    for (int off = 32; off; off >>= 1) s += __shfl_xor(s, off);
    if (c == 0) {
        if (dv <= 0.f) dv = 1.f;
        float v = s / dv + out_b[0];
        out[b] = 1.f / (1.f + __expf(-v));
    }
}

// ---------------- host ----------------

extern "C" void kernel_launch(void* const* d_in, const int* in_sizes, int n_in,
                              void* d_out, int out_size, void* d_ws, size_t ws_size,
                              hipStream_t stream) {
    const float* x         = (const float*)d_in[0];
    const float* edge_attr = (const float*)d_in[1];
    const int*   edge_src  = (const int*)d_in[2];
    const int*   edge_dst  = (const int*)d_in[3];
    const int*   batch     = (const int*)d_in[4];
    const float* node_W    = (const float*)d_in[5];
    const float* node_b    = (const float*)d_in[6];
    const float* edge_W    = (const float*)d_in[7];
    const float* edge_b    = (const float*)d_in[8];
    const float* Wq        = (const float*)d_in[9];
    const float* bq        = (const float*)d_in[10];
    const float* Wk        = (const float*)d_in[11];
    const float* bk        = (const float*)d_in[12];
    const float* Wv        = (const float*)d_in[13];
    const float* bv        = (const float*)d_in[14];
    const float* We        = (const float*)d_in[15];
    const float* be        = (const float*)d_in[16];
    const float* Wskip     = (const float*)d_in[17];
    const float* bskip     = (const float*)d_in[18];
    const float* gamma     = (const float*)d_in[19];
    const float* beta      = (const float*)d_in[20];
    const float* gate_W    = (const float*)d_in[21];
    const float* gate_b    = (const float*)d_in[22];
    const float* out_W     = (const float*)d_in[23];
    const float* out_b     = (const float*)d_in[24];
    float* out = (float*)d_out;

    const int N = in_sizes[0] / 16;
    const int E = in_sizes[2];
    const int nbl = (N + 31) / 32;   // layer blocks: 32 nodes per block

    char* ws = (char*)d_ws;
    size_t off = 0;
    auto alloc = [&](size_t bytes) {
        size_t o = off;
        off += (bytes + 255) & ~(size_t)255;
        return o;
    };
    float*    h        = (float*)(ws + alloc((size_t)N * 64 * 4));
    ushort_t* h_bf     = (ushort_t*)(ws + alloc((size_t)N * 64 * 2));
    float*    outbuf   = (float*)(ws + alloc((size_t)N * 64 * 4));
    int*      rowptr   = (int*)(ws + alloc((size_t)(N + 1) * 4));
    int*      cursor   = (int*)(ws + alloc((size_t)N * 4));
    int*      counts   = (int*)(ws + alloc((size_t)N * 4));
    int*      bsums    = (int*)(ws + alloc(1024));
    char*     erec     = (char*)(ws + alloc((size_t)E * 32));
    float*    Wc       = (float*)(ws + alloc(2 * 1024 * 4));
    float*    bcb      = (float*)(ws + alloc(2 * 128 * 4));
    ushort_t* Wall_arr = (ushort_t*)(ws + alloc(2 * 14336 * 2));
    float*    Wall_b   = (float*)(ws + alloc(2 * 224 * 4));
    ushort_t* wv_arr   = (ushort_t*)(ws + alloc(2 * 8192 * 2));
    float*    cst      = (float*)(ws + alloc(2 * 64 * 4));
    float*    bnsums   = (float*)(ws + alloc(128 * 4));
    float*    gatebuf  = (float*)(ws + alloc((size_t)N * 4));
    float*    part     = (float*)(ws + alloc((size_t)nbl * 128 * 4));
    float*    pacc     = (float*)(ws + alloc((size_t)512 * 64 * 4));
    float*    pden     = (float*)(ws + alloc(512 * 4));
    if (off > ws_size) return;

    int O0 = (N * 64 + 255) / 256;
    int O1 = O0 + (N + 255) / 256;
    int O2 = O1 + 9;
    int O3 = O2 + 178;   // 2*14336 + 2*224 + 2*8192 = 45504 -> 178 blocks
    setup_kernel<<<O3, 256, 0, stream>>>(
        x, node_W, node_b, edge_W, edge_b, We, be, Wq, bq, Wk, bk, Wv, bv, Wskip, bskip,
        h, h_bf, counts, Wc, bcb, Wall_arr, Wall_b, wv_arr, O0, O1, O2, N);
    combine2_kernel<<<10, 256, 0, stream>>>(Wq, bq, bk, bv, Wc, bcb, Wall_arr, Wall_b, cst);

    csr_count_kernel<<<(E + 255) / 256, 256, 0, stream>>>(edge_dst, counts, E);
    int nb = (N + 255) / 256;
    scan1_kernel<<<nb, 256, 0, stream>>>(counts, rowptr, bsums, N);
    scan3_kernel<<<nb, 256, 0, stream>>>(rowptr, bsums, cursor, N, E, nb);
    csr_fill_kernel<<<(E + 255) / 256, 256, 0, stream>>>(edge_dst, edge_src, edge_attr,
                                                         cursor, erec, E);

    // layer 0
    layer_kernel<<<nbl, 512, 0, stream>>>(h_bf, erec, rowptr,
                                          Wall_arr, Wall_b, wv_arr, Wc, cst,
                                          outbuf, part, N);
    bnreduce_kernel<<<128, 256, 0, stream>>>(part, bnsums, nbl);
    bnh_kernel<<<(N * 64 + 255) / 256, 256, 0, stream>>>(
        outbuf, bnsums, gamma, beta, h, h_bf, N);

    // layer 1
    layer_kernel<<<nbl, 512, 0, stream>>>(h_bf, erec, rowptr,
                                          Wall_arr + 14336, Wall_b + 224, wv_arr + 8192,
                                          Wc + 1024, cst + 64,
                                          outbuf, part, N);
    bnreduce_kernel<<<128, 256, 0, stream>>>(part, bnsums, nbl);
    bnapply_kernel<<<(N * 64 + 255) / 256, 256, 0, stream>>>(
        outbuf, bnsums, gamma + 64, beta + 64, gate_W, gate_b, h, gatebuf, N);

    pool_acc_kernel<<<512, 256, 0, stream>>>(h, gatebuf, batch, pacc, pden, N);
    pool_fin_kernel<<<64, 64, 0, stream>>>(pacc, pden, out_W, out_b, out);
}